// Round 4
// baseline (387.688 us; speedup 1.0000x reference)
//
#include <hip/hip_runtime.h>

#define NPTS 2048
#define LVLS 16
#define TS   524288        // 2^19 hash entries per level -> mask TS-1
#define FEAT 8
#define ROWS_PER_BLK 64
#define BLK 256
#define OUT_W (LVLS * NPTS)   // 32768

typedef float vfloat4 __attribute__((ext_vector_type(4)));

// out[i, l*N + j] = base_j + fx_i*dx_j + fy_i*dy_j + fz_i*dz_j   (1/3 folded in)
// base = (f0+f2+f4)/3, dx=(f1-f0)/3, dy=(f3-f2)/3, dz=(f5-f4)/3
//
// Block = (level, row-tile). Block covers ALL 2048 columns of its level:
// per row it writes one fully contiguous 8 KB span (2 x 1 KB per wave-store).
__global__ __launch_bounds__(BLK) void mrhe_kernel(const float* __restrict__ x,
                                                   const float* __restrict__ tables,
                                                   float* __restrict__ out) {
    const int level = blockIdx.x;                 // [0,16)
    const int row0  = blockIdx.y * ROWS_PER_BLK;  // [0,2048) step 64
    const int t     = threadIdx.x;

    const float gridres = (float)(1 << (level + 1));

    __shared__ vfloat4 fr[ROWS_PER_BLK];
    if (t < ROWS_PER_BLK) {
        const int i = row0 + t;
        const float sx = x[i * 3 + 0] * gridres;
        const float sy = x[i * 3 + 1] * gridres;
        const float sz = x[i * 3 + 2] * gridres;
        vfloat4 f;
        f.x = sx - floorf(sx);
        f.y = sy - floorf(sy);
        f.z = sz - floorf(sz);
        f.w = 0.0f;
        fr[t] = f;
    }

    // two column-quads per thread: cols 4t..4t+3 and 1024+4t..1024+4t+3
    const float* tl = tables + (size_t)level * TS * FEAT;
    const float third = 1.0f / 3.0f;
    vfloat4 baseA, dxA, dyA, dzA, baseB, dxB, dyB, dzB;
#pragma unroll
    for (int half = 0; half < 2; ++half) {
        vfloat4 bs, vx, vy, vz;
#pragma unroll
        for (int c = 0; c < 4; ++c) {
            const int j = half * 1024 + 4 * t + c;
            const float sx = x[j * 3 + 0] * gridres;
            const float sy = x[j * 3 + 1] * gridres;
            const float sz = x[j * 3 + 2] * gridres;
            // coords in [0,1): floors non-negative; sum < 3*2^16 < 2^19
            const int h = ((int)floorf(sx) + (int)floorf(sy) + (int)floorf(sz)) & (TS - 1);
            const vfloat4* fp = (const vfloat4*)(tl + (size_t)h * FEAT);
            const vfloat4 f03 = fp[0];   // f0 f1 f2 f3
            const vfloat4 f47 = fp[1];   // f4 f5 f6 f7
            bs[c] = (f03.x + f03.z + f47.x) * third;
            vx[c] = (f03.y - f03.x) * third;
            vy[c] = (f03.w - f03.z) * third;
            vz[c] = (f47.y - f47.x) * third;
        }
        if (half == 0) { baseA = bs; dxA = vx; dyA = vy; dzA = vz; }
        else           { baseB = bs; dxB = vx; dyB = vy; dzB = vz; }
    }
    __syncthreads();

    float* orow = out + (size_t)row0 * OUT_W + (size_t)level * NPTS;
#pragma unroll 4
    for (int i = 0; i < ROWS_PER_BLK; ++i) {
        const vfloat4 f = fr[i];          // ds_read_b128 broadcast (no conflict)
        vfloat4 oA = baseA + f.x * dxA + f.y * dyA + f.z * dzA;
        vfloat4 oB = baseB + f.x * dxB + f.y * dyB + f.z * dzB;
        *(vfloat4*)(orow + 4 * t)        = oA;   // 1 KB/wave, block row = 8 KB contiguous
        *(vfloat4*)(orow + 1024 + 4 * t) = oB;
        orow += OUT_W;
    }
}

extern "C" void kernel_launch(void* const* d_in, const int* in_sizes, int n_in,
                              void* d_out, int out_size, void* d_ws, size_t ws_size,
                              hipStream_t stream) {
    const float* x      = (const float*)d_in[0];   // [2048, 3]
    const float* tables = (const float*)d_in[1];   // [16, 524288, 8]
    float* out = (float*)d_out;                    // [2048, 16*2048]

    dim3 grid(LVLS, NPTS / ROWS_PER_BLK);          // 16 x 32 = 512 blocks
    dim3 block(BLK);
    mrhe_kernel<<<grid, block, 0, stream>>>(x, tables, out);
}